// Round 9
// baseline (53.085 us; speedup 1.0000x reference)
//
#include <hip/hip_runtime.h>
#include <hip/hip_bf16.h>

// ---- problem constants ----
#define BATCH 16
#define CIN   12
#define HIMG  512
#define WIMG  512
#define OCH   768
#define KDIM  256            // 16*16 patch
#define HW    (HIMG*WIMG)    // 262144
#define NPATCH 1024          // 32*32 patches per batch

typedef __attribute__((ext_vector_type(8))) short short8;   // 8 bf16 = 4 VGPRs
typedef __attribute__((ext_vector_type(4))) float f32x4;

// ---------------------------------------------------------------------------
// Kernel 0: convert + PACK weights f32 -> bf16 in MFMA fragment-lane order.
//   packed[u][0..7], u = (ot*8 + kk)*64 + lane holds
//   w[ot*16 + (lane&15)][kk*32 + (lane>>4)*8 + j], j=0..7.
// ---------------------------------------------------------------------------
__global__ void wpack_kernel(const float* __restrict__ w, short8* __restrict__ wbp) {
    int u = blockIdx.x * 256 + threadIdx.x;      // 0..24575
    int lane = u & 63;
    int kk   = (u >> 6) & 7;
    int ot   = u >> 9;                           // 0..47
    int o = ot * 16 + (lane & 15);
    int k = kk * 32 + (lane >> 4) * 8;
    const float* src = w + (size_t)o * KDIM + k;
    f32x4 v0 = *reinterpret_cast<const f32x4*>(src);
    f32x4 v1 = *reinterpret_cast<const f32x4*>(src + 4);
    union { short8 s; __hip_bfloat16 h[8]; } t;
    t.h[0] = __float2bfloat16(v0.x);
    t.h[1] = __float2bfloat16(v0.y);
    t.h[2] = __float2bfloat16(v0.z);
    t.h[3] = __float2bfloat16(v0.w);
    t.h[4] = __float2bfloat16(v1.x);
    t.h[5] = __float2bfloat16(v1.y);
    t.h[6] = __float2bfloat16(v1.z);
    t.h[7] = __float2bfloat16(v1.w);
    wbp[u] = t.s;
}

// ---------------------------------------------------------------------------
// Fused kernel: channel-mean + patch-embedding GEMM, HIGH OCCUPANCY version.
// 1024 blocks (4/CU resident at VGPR<=64) x 512 threads (8 waves).
// Block = (batch b, stripe is, column-half ch): 16 rows x 256 cols of the
// mean image = 16 patches, all 768 o-channels.  x is read exactly once
// grid-wide; no xm round-trip.
//   Phase 1: stream 12ch x 16rows x 256cols of x, mean in regs, bf16 ->
//            LDS tile Bl[patch j][k = r*16+s]   (2 quad-positions/thread).
//   Phase 2: wave wv owns o-range [wv*96, +96) x 16 patches = 6x1 fragments
//            of 16x16x32 bf16 MFMA, K=256 in 8 steps; A-fragments are
//            coalesced 1 KiB wave loads from L2-resident packed weights;
//            acc[6] = only 24 VGPR -> fits the 64-VGPR / 32-wave regime.
// Cross-phase overlap across the 4 resident blocks hides staging latency.
// ---------------------------------------------------------------------------
#define LDB 264   // 256 + 8 pad

__global__ __launch_bounds__(512, 8) void fused_kernel(
        const short8* __restrict__ wbp,   // packed weights (L2-resident)
        const float*  __restrict__ x,     // [B][C][H][W]
        const float*  __restrict__ bias,
        float* __restrict__ out) {        // [B][O][32][32]
    __shared__ short Bl[16][LDB];

    const int tid = threadIdx.x;
    const int bid = blockIdx.x;
    const int b  = bid >> 6;              // 64 (is,ch) blocks per batch
    const int is = (bid >> 1) & 31;       // stripe / patch-row index
    const int ch = bid & 1;               // column half

    // ---- phase 1: channel mean of 16 rows x 256 cols -> LDS ----
    {
        const float inv = 1.0f / 12.0f;
        #pragma unroll
        for (int half = 0; half < 2; ++half) {
            const int pos = half * 512 + tid;   // 0..1023 quad positions
            const int r   = pos >> 6;           // image row 0..15
            const int qc  = pos & 63;           // quad col (4 f32 each)
            const float* px = x + (size_t)b * CIN * HW
                              + (size_t)(is * 16 + r) * WIMG + ch * 256 + qc * 4;
            float sx = 0.f, sy = 0.f, sz = 0.f, sw = 0.f;
            #pragma unroll
            for (int c = 0; c < CIN; ++c) {
                f32x4 v = *reinterpret_cast<const f32x4*>(px + (size_t)c * HW);
                sx += v.x; sy += v.y; sz += v.z; sw += v.w;
            }
            union { ushort4 u4; __hip_bfloat16 h[4]; } o;
            o.h[0] = __float2bfloat16(sx * inv);
            o.h[1] = __float2bfloat16(sy * inv);
            o.h[2] = __float2bfloat16(sz * inv);
            o.h[3] = __float2bfloat16(sw * inv);
            // patch j = qc>>2, k = r*16 + (qc&3)*4
            *reinterpret_cast<ushort4*>(&Bl[qc >> 2][r * 16 + (qc & 3) * 4]) = o.u4;
        }
    }
    __syncthreads();

    // ---- phase 2: MFMA ----
    const int lane = tid & 63;
    const int wv   = tid >> 6;           // 0..7
    const int lrow = lane & 15;
    const int lg   = lane >> 4;

    f32x4 acc[6] = {};
    const short8* wp = wbp + (size_t)(wv * 6) * 8 * 64 + lane;  // fo=0,kk=0

    #pragma unroll
    for (int kk = 0; kk < 8; ++kk) {
        const short8 bf = *reinterpret_cast<const short8*>(&Bl[lrow][kk * 32 + lg * 8]);
        #pragma unroll
        for (int fo = 0; fo < 6; ++fo) {
            const short8 af = wp[(size_t)(fo * 8 + kk) * 64];
            acc[fo] = __builtin_amdgcn_mfma_f32_16x16x32_bf16(af, bf, acc[fo], 0, 0, 0);
        }
    }

    // ---- epilogue: D row = o ((lane>>4)*4 + reg), col = m (lane&15) ----
    const int p0 = is * 32 + ch * 16;
    float* ob = out + (size_t)b * OCH * NPATCH + p0;
    #pragma unroll
    for (int fo = 0; fo < 6; ++fo) {
        const int obase = wv * 96 + fo * 16 + lg * 4;
        #pragma unroll
        for (int r = 0; r < 4; ++r) {
            const int o = obase + r;
            ob[(size_t)o * NPATCH + lrow] = acc[fo][r] + bias[o];
        }
    }
}

// ---------------------------------------------------------------------------
extern "C" void kernel_launch(void* const* d_in, const int* in_sizes, int n_in,
                              void* d_out, int out_size, void* d_ws, size_t ws_size,
                              hipStream_t stream) {
    const float* x    = (const float*)d_in[0];
    const float* w    = (const float*)d_in[1];
    const float* bias = (const float*)d_in[2];
    float* out = (float*)d_out;

    short8* wbp = (short8*)d_ws;   // 384 KiB packed bf16 weights

    wpack_kernel<<<96, 256, 0, stream>>>(w, wbp);
    fused_kernel<<<1024, 512, 0, stream>>>(wbp, x, bias, out);
}